// Round 3
// baseline (817.047 us; speedup 1.0000x reference)
//
#include <hip/hip_runtime.h>
#include <math.h>

// Problem constants
#define C 256
#define K 1024
#define SS 4096          // 16*16*16 spatial
#define NB 8             // batch
#define NN 32768         // NB*SS rows
#define ZQ_ELEMS 8388608 // NB*C*SS
#define OUT_LOSS 8388608
#define OUT_PERP 8388609
#define OUT_IDX  8388610
#define OUT_MD   8421378

// workspace float layout
#define WS_SZ2   0       // sum z^2 (scalar)
#define WS_SE2   1       // sum e^2 (scalar)
#define WS_LOSS  2       // sum (zq-z)^2 (scalar)
#define WS_ZSUM  8       // [256] column sums of zf
#define WS_ESUM  264     // [256] column sums of emb
#define WS_CNT   520     // [1024] histogram (float)
#define WS_E2R   1544    // [1024] ||e_k||^2, numpy-pairwise f32
#define WS_Z2N   2568    // [32768] ||z_n||^2, numpy-pairwise f32
#define WS_FLG   35336   // int region: [0]=count, [1..32768]=rows

#define FLAG_EPS 1.2e-4f

// ---- numpy pairwise f32 sum of squares, 256 contiguous elements ----
// numpy: n=256 -> split 128+128; each 128 = 8-accumulator unrolled loop,
// combine ((r0+r1)+(r2+r3))+((r4+r5)+(r6+r7)); total = left + right.
// __f*_rn intrinsics block FMA contraction (numpy squares into a temp, then adds).
__device__ inline float np_sumsq_256(const float* __restrict__ a) {
  float tot = 0.f;
  #pragma unroll
  for (int h = 0; h < 2; ++h) {
    const float* p = a + 128 * h;
    float r[8];
    #pragma unroll
    for (int j = 0; j < 8; ++j) r[j] = __fmul_rn(p[j], p[j]);
    for (int i = 8; i < 128; i += 8) {
      #pragma unroll
      for (int j = 0; j < 8; ++j) {
        float v = p[i + j];
        r[j] = __fadd_rn(r[j], __fmul_rn(v, v));
      }
    }
    float s01 = __fadd_rn(r[0], r[1]);
    float s23 = __fadd_rn(r[2], r[3]);
    float s45 = __fadd_rn(r[4], r[5]);
    float s67 = __fadd_rn(r[6], r[7]);
    float res = __fadd_rn(__fadd_rn(s01, s23), __fadd_rn(s45, s67));
    tot = (h == 0) ? res : __fadd_rn(tot, res);
  }
  return tot;
}

// ---------- e2[k] = numpy-pairwise ||e_k||^2 ; also Se2 ----------
__global__ void e2_np_k(const float* __restrict__ emb, float* __restrict__ ws) {
  int k = blockIdx.x * 256 + threadIdx.x;  // 4 blocks x 256
  float tot = np_sumsq_256(emb + (size_t)k * C);
  ws[WS_E2R + k] = tot;
  atomicAdd(&ws[WS_SE2], tot);
}

// ---------- emb column sums (for mean_distance) ----------
__global__ void emb_col_k(const float* __restrict__ emb, float* __restrict__ ws) {
  int j = blockIdx.x;      // 64 blocks, 16 rows each
  int c = threadIdx.x;     // 256
  float s = 0.f;
  #pragma unroll
  for (int i = 0; i < 16; ++i) s += emb[(size_t)(j * 16 + i) * C + c];
  atomicAdd(&ws[WS_ESUM + c], s);
}

// ---------- z stats: zsum[c], Sz2 (for mean_distance) ----------
__global__ void z_stats_k(const float* __restrict__ z, float* __restrict__ ws) {
  __shared__ float sc[8];
  int blk = blockIdx.x;    // b*256 + c (2048 blocks)
  int t = threadIdx.x;
  const float4* zp = (const float4*)(z + (size_t)blk * SS);
  float sum = 0.f, sq = 0.f;
  #pragma unroll
  for (int i = 0; i < 4; ++i) {
    float4 v = zp[t + 256 * i];
    sum += v.x + v.y + v.z + v.w;
    sq  += v.x * v.x + v.y * v.y + v.z * v.z + v.w * v.w;
  }
  #pragma unroll
  for (int off = 32; off; off >>= 1) {
    sum += __shfl_down(sum, off);
    sq  += __shfl_down(sq, off);
  }
  int lane = t & 63, w = t >> 6;
  if (lane == 0) { sc[w] = sum; sc[4 + w] = sq; }
  __syncthreads();
  if (t == 0) {
    atomicAdd(&ws[WS_ZSUM + (blk & 255)], sc[0] + sc[1] + sc[2] + sc[3]);
    atomicAdd(&ws[WS_SZ2], sc[4] + sc[5] + sc[6] + sc[7]);
  }
}

#define MROWS 64
#define KT 64
#define ZS_STRIDE 260

// ---------- z2[n] = numpy-pairwise ||z_n||^2 (rows staged via LDS) ----------
__global__ __launch_bounds__(256)
void z2_np_k(const float* __restrict__ z, float* __restrict__ z2np) {
  extern __shared__ float zs[];  // 64*260
  const int t  = threadIdx.x;
  const int n0 = blockIdx.x * MROWS;
  const int b  = n0 / SS;
  const int s0 = n0 % SS;
  {
    const int sl = t & 63, cg = t >> 6;
    const float* zb = z + (size_t)b * C * SS + s0 + sl;
    #pragma unroll
    for (int i = 0; i < 16; ++i) {
      int c = (cg * 16 + i) * 4;
      float4 v;
      v.x = zb[(size_t)(c + 0) * SS];
      v.y = zb[(size_t)(c + 1) * SS];
      v.z = zb[(size_t)(c + 2) * SS];
      v.w = zb[(size_t)(c + 3) * SS];
      *(float4*)&zs[sl * ZS_STRIDE + c] = v;
    }
  }
  __syncthreads();
  if (t < MROWS) z2np[n0 + t] = np_sumsq_256(&zs[t * ZS_STRIDE]);
}

// ---------- main: fp32 quantized scores + top-2 argmin + ambiguity flags ----------
// score(n,k) = fl32( fl32(z2_n + e2_k) - 2*dot ) : replicates np expansion formula.
__global__ __launch_bounds__(256)
void vq_main_k(const float* __restrict__ z, const float* __restrict__ emb,
               const float* __restrict__ e2row, const float* __restrict__ z2np,
               float* __restrict__ out_idx, int* __restrict__ flags) {
  extern __shared__ float smem[];
  float* zs    = smem;                       // 64*260
  float* es    = smem + MROWS * ZS_STRIDE;   // 64*260
  float* e2s   = es + KT * ZS_STRIDE;        // 64
  float* z2s   = e2s + 64;                   // 64
  float* redv1 = z2s + 64;                   // 64*17
  float* redi1 = redv1 + 64 * 17;            // 64*17
  float* redv2 = redi1 + 64 * 17;            // 64*17

  const int t  = threadIdx.x;
  const int n0 = blockIdx.x * MROWS;
  const int b  = n0 / SS;
  const int s0 = n0 % SS;

  {
    const int sl = t & 63, cg = t >> 6;
    const float* zb = z + (size_t)b * C * SS + s0 + sl;
    #pragma unroll
    for (int i = 0; i < 16; ++i) {
      int c = (cg * 16 + i) * 4;
      float4 v;
      v.x = zb[(size_t)(c + 0) * SS];
      v.y = zb[(size_t)(c + 1) * SS];
      v.z = zb[(size_t)(c + 2) * SS];
      v.w = zb[(size_t)(c + 3) * SS];
      *(float4*)&zs[sl * ZS_STRIDE + c] = v;
    }
    if (t < MROWS) z2s[t] = z2np[n0 + t];
  }

  const int ti = t & 15, tj = t >> 4;
  float v1[4], v2[4];
  int   i1[4];
  #pragma unroll
  for (int a = 0; a < 4; ++a) { v1[a] = 3.4e38f; v2[a] = 3.4e38f; i1[a] = 0; }

  for (int k0 = 0; k0 < K; k0 += KT) {
    __syncthreads();
    {
      const float4* eg = (const float4*)(emb + (size_t)k0 * C);
      #pragma unroll
      for (int i = 0; i < 16; ++i) {
        int f = t + 256 * i;
        int kr = f >> 6, c4 = f & 63;
        ((float4*)&es[kr * ZS_STRIDE])[c4] = eg[kr * 64 + c4];
      }
      if (t < KT) e2s[t] = e2row[k0 + t];
    }
    __syncthreads();

    float acc[4][4];
    #pragma unroll
    for (int a = 0; a < 4; ++a)
      #pragma unroll
      for (int bb = 0; bb < 4; ++bb) acc[a][bb] = 0.f;

    for (int c4 = 0; c4 < 64; ++c4) {
      float4 zv[4], ev[4];
      #pragma unroll
      for (int a = 0; a < 4; ++a)
        zv[a] = *(const float4*)&zs[(ti + 16 * a) * ZS_STRIDE + 4 * c4];
      #pragma unroll
      for (int bb = 0; bb < 4; ++bb)
        ev[bb] = *(const float4*)&es[(tj + 16 * bb) * ZS_STRIDE + 4 * c4];
      #pragma unroll
      for (int a = 0; a < 4; ++a)
        #pragma unroll
        for (int bb = 0; bb < 4; ++bb)
          acc[a][bb] += zv[a].x * ev[bb].x + zv[a].y * ev[bb].y
                      + zv[a].z * ev[bb].z + zv[a].w * ev[bb].w;
    }

    #pragma unroll
    for (int bb = 0; bb < 4; ++bb) {
      int kk = tj + 16 * bb;
      float e2 = e2s[kk];
      int kg = k0 + kk;
      #pragma unroll
      for (int a = 0; a < 4; ++a) {
        float t1 = __fadd_rn(z2s[ti + 16 * a], e2);
        float sv = __fsub_rn(t1, __fmul_rn(2.f, acc[a][bb]));
        if (sv < v1[a]) { v2[a] = v1[a]; v1[a] = sv; i1[a] = kg; }
        else if (sv < v2[a]) { v2[a] = sv; }
      }
    }
  }
  __syncthreads();

  #pragma unroll
  for (int a = 0; a < 4; ++a) {
    int r = ti + 16 * a;
    redv1[r * 17 + tj] = v1[a];
    redi1[r * 17 + tj] = (float)i1[a];
    redv2[r * 17 + tj] = v2[a];
  }
  __syncthreads();
  if (t < MROWS) {
    float bv1 = redv1[t * 17];
    int   bi  = (int)redi1[t * 17];
    float bv2 = redv2[t * 17];
    #pragma unroll
    for (int j = 1; j < 16; ++j) {
      float v  = redv1[t * 17 + j];
      int   ii = (int)redi1[t * 17 + j];
      float w2 = redv2[t * 17 + j];
      if (v < bv1) { bv2 = fminf(bv1, w2); bv1 = v; bi = ii; }
      else {
        if (v == bv1 && ii < bi) bi = ii;
        bv2 = fminf(bv2, v);
      }
    }
    out_idx[n0 + t] = (float)bi;
    if (bv2 - bv1 < FLAG_EPS) {
      int p = atomicAdd(&flags[0], 1);
      if (p < NN) flags[1 + p] = n0 + t;
    }
  }
}

// ---------- fixup: exactly-rounded f32 dot (via f64) for ambiguous rows ----------
__global__ __launch_bounds__(256)
void fixup_k(const float* __restrict__ z, const float* __restrict__ emb,
             const float* __restrict__ e2np, const float* __restrict__ z2np,
             const int* __restrict__ flags, float* __restrict__ out_idx) {
  __shared__ float zrow[C];
  __shared__ float bval[4];
  __shared__ int   bidx[4];
  int cnt = flags[0];
  if (cnt > NN) cnt = NN;
  for (int f = blockIdx.x; f < cnt; f += gridDim.x) {
    int n = flags[1 + f];
    int b = n >> 12, s = n & (SS - 1);
    int t = threadIdx.x;
    zrow[t] = z[((size_t)(b * C + t) << 12) + s];
    __syncthreads();
    float z2 = z2np[n];
    float best = 3.4e38f; int besti = 0x7fffffff;
    for (int kk = t; kk < K; kk += 256) {
      const float* er = emb + (size_t)kk * C;
      double acc = 0.0;
      #pragma unroll 4
      for (int c = 0; c < C; ++c)
        acc = fma((double)zrow[c], (double)er[c], acc);
      float g  = (float)acc;  // round-to-nearest f32 of exact dot
      float t1 = __fadd_rn(z2, e2np[kk]);
      float d  = __fsub_rn(t1, __fmul_rn(2.f, g));  // np's quantized score
      if (d < best) { best = d; besti = kk; }
    }
    #pragma unroll
    for (int off = 32; off; off >>= 1) {
      float ov = __shfl_down(best, off);
      int   oi = __shfl_down(besti, off);
      if (ov < best || (ov == best && oi < besti)) { best = ov; besti = oi; }
    }
    int lane = t & 63, w = t >> 6;
    if (lane == 0) { bval[w] = best; bidx[w] = besti; }
    __syncthreads();
    if (t == 0) {
      #pragma unroll
      for (int w2 = 1; w2 < 4; ++w2) {
        if (bval[w2] < best || (bval[w2] == best && bidx[w2] < besti)) {
          best = bval[w2]; besti = bidx[w2];
        }
      }
      out_idx[n] = (float)besti;
    }
    __syncthreads();
  }
}

// ---------- histogram from final idx ----------
__global__ void hist_k(const float* __restrict__ idxf, float* __restrict__ counts) {
  int n = blockIdx.x * 256 + threadIdx.x;
  atomicAdd(&counts[(int)idxf[n]], 1.0f);
}

// ---------- gather zq + loss accumulation ----------
__global__ __launch_bounds__(256)
void gather_loss_k(const float* __restrict__ z, const float* __restrict__ emb,
                   float* __restrict__ out, float* __restrict__ ws) {
  __shared__ float sc[4];
  int f = blockIdx.x * 256 + threadIdx.x;  // float4 id
  int i = f << 2;
  int b = i >> 20;
  int rem = i & ((1 << 20) - 1);
  int c = rem >> 12;
  int s = rem & (SS - 1);
  int n = (b << 12) | s;
  const float* idxf = out + OUT_IDX;
  float2 ia = *(const float2*)(idxf + n);
  float2 ib = *(const float2*)(idxf + n + 2);
  int i0 = (int)ia.x, i1 = (int)ia.y, i2 = (int)ib.x, i3 = (int)ib.y;
  float4 q;
  q.x = emb[(size_t)i0 * C + c];
  q.y = emb[(size_t)i1 * C + c];
  q.z = emb[(size_t)i2 * C + c];
  q.w = emb[(size_t)i3 * C + c];
  float4 zv = *(const float4*)(z + i);
  float dx = q.x - zv.x, dy = q.y - zv.y, dz = q.z - zv.z, dw = q.w - zv.w;
  float l = dx * dx + dy * dy + dz * dz + dw * dw;
  *(float4*)(out + i) = q;
  #pragma unroll
  for (int off = 32; off; off >>= 1) l += __shfl_down(l, off);
  int lane = threadIdx.x & 63, w = threadIdx.x >> 6;
  if (lane == 0) sc[w] = l;
  __syncthreads();
  if (threadIdx.x == 0)
    atomicAdd(&ws[WS_LOSS], sc[0] + sc[1] + sc[2] + sc[3]);
}

// ---------- finalize scalars ----------
__global__ void finalize_k(const float* __restrict__ ws, float* __restrict__ out) {
  __shared__ float sc[8];
  int t = threadIdx.x;
  float ent = 0.f;
  #pragma unroll
  for (int k = t; k < K; k += 256) {
    float em = ws[WS_CNT + k] * (1.0f / NN);
    ent += em * logf(em + 1e-10f);
  }
  float zd = ws[WS_ZSUM + t] * ws[WS_ESUM + t];
  #pragma unroll
  for (int off = 32; off; off >>= 1) {
    ent += __shfl_down(ent, off);
    zd  += __shfl_down(zd, off);
  }
  int lane = t & 63, w = t >> 6;
  if (lane == 0) { sc[w] = ent; sc[4 + w] = zd; }
  __syncthreads();
  if (t == 0) {
    ent = sc[0] + sc[1] + sc[2] + sc[3];
    zd  = sc[4] + sc[5] + sc[6] + sc[7];
    out[OUT_LOSS] = 1.25f * ws[WS_LOSS] * (1.0f / ZQ_ELEMS);  // (1+beta)*MSE
    out[OUT_PERP] = expf(-ent);
    out[OUT_MD]   = ws[WS_SZ2] * (1.0f / NN) + ws[WS_SE2] * (1.0f / K)
                  - 2.0f * zd * (1.0f / ((float)NN * (float)K));
  }
}

extern "C" void kernel_launch(void* const* d_in, const int* in_sizes, int n_in,
                              void* d_out, int out_size, void* d_ws, size_t ws_size,
                              hipStream_t stream) {
  const float* z   = (const float*)d_in[0];
  const float* emb = (const float*)d_in[1];
  float* out = (float*)d_out;
  float* ws  = (float*)d_ws;
  int* flags = (int*)(ws + WS_FLG);
  (void)in_sizes; (void)n_in; (void)out_size; (void)ws_size;

  hipMemsetAsync(d_ws, 0, (WS_FLG + 1) * sizeof(float), stream);
  e2_np_k<<<K / 256, 256, 0, stream>>>(emb, ws);
  emb_col_k<<<64, 256, 0, stream>>>(emb, ws);
  z_stats_k<<<NB * C, 256, 0, stream>>>(z, ws);
  z2_np_k<<<NN / MROWS, 256, MROWS * ZS_STRIDE * sizeof(float), stream>>>(z, ws + WS_Z2N);
  size_t lds = (2 * MROWS * ZS_STRIDE + 128 + 3 * 64 * 17) * sizeof(float);
  vq_main_k<<<NN / MROWS, 256, lds, stream>>>(z, emb, ws + WS_E2R, ws + WS_Z2N,
                                              out + OUT_IDX, flags);
  fixup_k<<<256, 256, 0, stream>>>(z, emb, ws + WS_E2R, ws + WS_Z2N, flags, out + OUT_IDX);
  hist_k<<<NN / 256, 256, 0, stream>>>(out + OUT_IDX, ws + WS_CNT);
  gather_loss_k<<<ZQ_ELEMS / 1024, 256, 0, stream>>>(z, emb, out, ws);
  finalize_k<<<1, 256, 0, stream>>>(ws, out);
}

// Round 5
// 459.907 us; speedup vs baseline: 1.7765x; 1.7765x over previous
//
#include <hip/hip_runtime.h>
#include <math.h>

// Problem constants
#define C 256
#define K 1024
#define SS 4096          // 16*16*16 spatial
#define NB 8             // batch
#define NN 32768         // NB*SS rows
#define ZQ_ELEMS 8388608 // NB*C*SS
#define OUT_LOSS 8388608
#define OUT_PERP 8388609
#define OUT_IDX  8388610
#define OUT_MD   8421378

// workspace float layout
#define WS_SZ2   0       // sum z^2 (scalar)
#define WS_SE2   1       // sum e^2 (scalar)
#define WS_LOSS  2       // sum (zq-z)^2 (scalar)
#define WS_ZSUM  8       // [256] column sums of zf
#define WS_ESUM  264     // [256] column sums of emb
#define WS_CNT   520     // [1024] histogram (float)
#define WS_E2R   1544    // [1024] ||e_k||^2, numpy-pairwise f32
#define WS_Z2N   2568    // [32768] ||z_n||^2, numpy-pairwise f32
#define WS_FLG   35336   // int region: [0]=count, [1..NN]=rows

#define T_FLAG 1.0e-4f   // flag if top-2 gap of u=e2-2g below this

typedef __attribute__((ext_vector_type(8))) short short8;
typedef __attribute__((ext_vector_type(4))) float f32x4;
typedef unsigned short u16;

__device__ inline u16 f2bf(float x) {  // f32 -> bf16 RNE
  unsigned u = __float_as_uint(x);
  unsigned r = (u + 0x7fffu + ((u >> 16) & 1u)) >> 16;
  return (u16)r;
}
__device__ inline float bf2f(u16 h) { return __uint_as_float(((unsigned)h) << 16); }

// ---- numpy pairwise f32 sum of squares, 256 contiguous elements ----
__device__ inline float np_sumsq_256(const float* __restrict__ a) {
  float tot = 0.f;
  #pragma unroll
  for (int h = 0; h < 2; ++h) {
    const float* p = a + 128 * h;
    float r[8];
    #pragma unroll
    for (int j = 0; j < 8; ++j) r[j] = __fmul_rn(p[j], p[j]);
    for (int i = 8; i < 128; i += 8) {
      #pragma unroll
      for (int j = 0; j < 8; ++j) {
        float v = p[i + j];
        r[j] = __fadd_rn(r[j], __fmul_rn(v, v));
      }
    }
    float s01 = __fadd_rn(r[0], r[1]);
    float s23 = __fadd_rn(r[2], r[3]);
    float s45 = __fadd_rn(r[4], r[5]);
    float s67 = __fadd_rn(r[6], r[7]);
    float res = __fadd_rn(__fadd_rn(s01, s23), __fadd_rn(s45, s67));
    tot = (h == 0) ? res : __fadd_rn(tot, res);
  }
  return tot;
}

// ---------- e2[k] = numpy-pairwise ||e_k||^2 ; also Se2 ----------
__global__ void e2_np_k(const float* __restrict__ emb, float* __restrict__ ws) {
  int k = blockIdx.x * 256 + threadIdx.x;  // 4 blocks x 256
  float tot = np_sumsq_256(emb + (size_t)k * C);
  ws[WS_E2R + k] = tot;
  atomicAdd(&ws[WS_SE2], tot);
}

// ---------- emb column sums (for mean_distance) ----------
__global__ void emb_col_k(const float* __restrict__ emb, float* __restrict__ ws) {
  int j = blockIdx.x;      // 64 blocks, 16 rows each
  int c = threadIdx.x;     // 256
  float s = 0.f;
  #pragma unroll
  for (int i = 0; i < 16; ++i) s += emb[(size_t)(j * 16 + i) * C + c];
  atomicAdd(&ws[WS_ESUM + c], s);
}

#define MROWS 64
#define ZS_STRIDE 260

// ---------- one pass over z: zsum[c], Sz2, z2np[n], bf16 split zh/zl ----------
__global__ __launch_bounds__(256)
void prep_z_k(const float* __restrict__ z, float* __restrict__ ws,
              u16* __restrict__ zh_g, u16* __restrict__ zl_g) {
  __shared__ float zs[MROWS * ZS_STRIDE];
  const int t = threadIdx.x;
  const int n0 = blockIdx.x * MROWS;
  const int b = n0 / SS;
  const int s0 = n0 % SS;
  {
    const int sl = t & 63, cg = t >> 6;
    const float* zb = z + (size_t)b * C * SS + s0 + sl;
    #pragma unroll
    for (int i = 0; i < 16; ++i) {
      int c = (cg * 16 + i) * 4;
      float4 v;
      v.x = zb[(size_t)(c + 0) * SS];
      v.y = zb[(size_t)(c + 1) * SS];
      v.z = zb[(size_t)(c + 2) * SS];
      v.w = zb[(size_t)(c + 3) * SS];
      *(float4*)&zs[sl * ZS_STRIDE + c] = v;
    }
  }
  __syncthreads();
  // column sums (thread t = channel c)
  {
    float s = 0.f;
    #pragma unroll 8
    for (int r = 0; r < MROWS; ++r) s += zs[r * ZS_STRIDE + t];
    atomicAdd(&ws[WS_ZSUM + t], s);
  }
  // bf16 split, row-major [n][c]
  {
    int r = t >> 2, q = t & 3;
    u16* zh_o = zh_g + (size_t)(n0 + r) * C;
    u16* zl_o = zl_g + (size_t)(n0 + r) * C;
    #pragma unroll
    for (int j = 0; j < 16; ++j) {
      int c = q * 64 + j * 4;
      float4 v = *(const float4*)&zs[r * ZS_STRIDE + c];
      u16 h0 = f2bf(v.x), h1 = f2bf(v.y), h2 = f2bf(v.z), h3 = f2bf(v.w);
      ushort4 hv = make_ushort4(h0, h1, h2, h3);
      ushort4 lv = make_ushort4(f2bf(v.x - bf2f(h0)), f2bf(v.y - bf2f(h1)),
                                f2bf(v.z - bf2f(h2)), f2bf(v.w - bf2f(h3)));
      *(ushort4*)&zh_o[c] = hv;
      *(ushort4*)&zl_o[c] = lv;
    }
  }
  // z2 (numpy-pairwise) + Sz2
  if (t < MROWS) {
    float z2 = np_sumsq_256(&zs[t * ZS_STRIDE]);
    ws[WS_Z2N + n0 + t] = z2;
    #pragma unroll
    for (int off = 32; off; off >>= 1) z2 += __shfl_down(z2, off);
    if (t == 0) atomicAdd(&ws[WS_SZ2], z2);
  }
}

// ---------- main: split-bf16 MFMA distances + top-2 argmin + flags ----------
// grid 256 x 256. Block tile 128 rows x (8 n-tiles of 128 codes).
// EACH WAVE OWNS FULL ROWS: wave w -> rows w*32..w*32+31 (mi 0..1), ALL 128
// cols (ni 0..7). No cross-wave merge, no out_idx write conflicts.
#define BM 128
#define BN 128
#define CH 64

__global__ __launch_bounds__(256)
void vq_mfma_k(const u16* __restrict__ zh_g, const u16* __restrict__ zl_g,
               const float* __restrict__ emb, const float* __restrict__ e2row,
               float* __restrict__ out_idx, int* __restrict__ flags) {
  extern __shared__ u16 smem_u16[];
  u16* Ah = smem_u16;            // [128 rows][64 c], row stride 64 u16, swizzled
  u16* Al = Ah + BM * CH;
  u16* Bh = Al + BM * CH;
  u16* Bl = Bh + BN * CH;
  float* e2s = (float*)(Bl + BN * CH);  // [128]

  const int t = threadIdx.x;
  const int lane = t & 63;
  const int wid = t >> 6;        // 0..3, wave owns rows wid*32..wid*32+31
  const int row0 = blockIdx.x * BM;

  // per-lane top-2 state: 8 row-slots (mi*4 + r)
  float v1[8], v2[8], i1f[8];
  #pragma unroll
  for (int s = 0; s < 8; ++s) { v1[s] = 3.4e38f; v2[s] = 3.4e38f; i1f[s] = 0.f; }

  for (int nt = 0; nt < K / BN; ++nt) {
    const int kc0 = nt * BN;
    __syncthreads();                 // prior n-tile's e2s readers done
    if (t < BN) e2s[t] = e2row[kc0 + t];

    f32x4 acc[2][8];
    #pragma unroll
    for (int mi = 0; mi < 2; ++mi)
      #pragma unroll
      for (int ni = 0; ni < 8; ++ni) acc[mi][ni] = (f32x4){0.f, 0.f, 0.f, 0.f};

    for (int ch = 0; ch < C / CH; ++ch) {
      const int c0 = ch * CH;
      __syncthreads();               // prior chunk's frag readers done
      // ---- stage A (pre-split bf16 rows) ----
      {
        const int g = t & 7;
        #pragma unroll
        for (int r = 0; r < 4; ++r) {
          int row = (t >> 3) + 32 * r;            // 0..127
          int jpos = g ^ (row & 7);               // swizzle
          size_t src = (size_t)(row0 + row) * C + c0 + g * 8;
          *(short8*)&Ah[row * CH + jpos * 8] = *(const short8*)&zh_g[src];
          *(short8*)&Al[row * CH + jpos * 8] = *(const short8*)&zl_g[src];
        }
      }
      // ---- stage B (split emb f32 -> bf16 hi/lo on the fly) ----
      {
        const int g = t & 7;
        #pragma unroll
        for (int r = 0; r < 4; ++r) {
          int row = (t >> 3) + 32 * r;            // code row 0..127
          int jpos = g ^ (row & 7);
          const float* src = emb + (size_t)(kc0 + row) * C + c0 + g * 8;
          float4 f0 = *(const float4*)src;
          float4 f1 = *(const float4*)(src + 4);
          float f[8] = {f0.x, f0.y, f0.z, f0.w, f1.x, f1.y, f1.z, f1.w};
          short8 hv, lv;
          #pragma unroll
          for (int j = 0; j < 8; ++j) {
            u16 h = f2bf(f[j]);
            hv[j] = (short)h;
            lv[j] = (short)f2bf(f[j] - bf2f(h));
          }
          *(short8*)&Bh[row * CH + jpos * 8] = hv;
          *(short8*)&Bl[row * CH + jpos * 8] = lv;
        }
      }
      __syncthreads();
      // ---- compute: 2 k-steps of 32 ----
      #pragma unroll
      for (int s = 0; s < 2; ++s) {
        const int q = s * 4 + (lane >> 4);
        short8 afh[2], afl[2];
        #pragma unroll
        for (int mi = 0; mi < 2; ++mi) {
          int rowl = wid * 32 + mi * 16 + (lane & 15);
          int jp = q ^ (rowl & 7);
          afh[mi] = *(short8*)&Ah[rowl * CH + jp * 8];
          afl[mi] = *(short8*)&Al[rowl * CH + jp * 8];
        }
        #pragma unroll
        for (int ni = 0; ni < 8; ++ni) {
          int rowb = ni * 16 + (lane & 15);
          int jp = q ^ (rowb & 7);
          short8 bh = *(short8*)&Bh[rowb * CH + jp * 8];
          short8 bl = *(short8*)&Bl[rowb * CH + jp * 8];
          #pragma unroll
          for (int mi = 0; mi < 2; ++mi) {
            acc[mi][ni] = __builtin_amdgcn_mfma_f32_16x16x32_bf16(afh[mi], bh, acc[mi][ni], 0, 0, 0);
            acc[mi][ni] = __builtin_amdgcn_mfma_f32_16x16x32_bf16(afh[mi], bl, acc[mi][ni], 0, 0, 0);
            acc[mi][ni] = __builtin_amdgcn_mfma_f32_16x16x32_bf16(afl[mi], bh, acc[mi][ni], 0, 0, 0);
          }
        }
      }
    }
    // ---- scoring: u = e2 - 2*g ; running top-2 per row-slot ----
    #pragma unroll
    for (int ni = 0; ni < 8; ++ni) {
      int col = ni * 16 + (lane & 15);
      float e2c = e2s[col];
      float kidx = (float)(kc0 + col);
      #pragma unroll
      for (int mi = 0; mi < 2; ++mi)
        #pragma unroll
        for (int r = 0; r < 4; ++r) {
          float sv = fmaf(-2.f, acc[mi][ni][r], e2c);
          int slot = mi * 4 + r;
          if (sv < v1[slot]) { v2[slot] = v1[slot]; v1[slot] = sv; i1f[slot] = kidx; }
          else if (sv < v2[slot]) v2[slot] = sv;
        }
    }
  }
  // ---- butterfly top-2 merge over the 16 lanes sharing (lane>>4) ----
  #pragma unroll
  for (int off = 1; off < 16; off <<= 1) {
    #pragma unroll
    for (int s = 0; s < 8; ++s) {
      float ov1 = __shfl_xor(v1[s], off);
      float oi1 = __shfl_xor(i1f[s], off);
      float ov2 = __shfl_xor(v2[s], off);
      bool take = (ov1 < v1[s]) || (ov1 == v1[s] && oi1 < i1f[s]);
      float nv2 = fminf(take ? v1[s] : v2[s], take ? ov2 : ov1);
      if (take) { v1[s] = ov1; i1f[s] = oi1; }
      v2[s] = nv2;
    }
  }
  if ((lane & 15) == 0) {
    int q = lane >> 4;
    #pragma unroll
    for (int mi = 0; mi < 2; ++mi)
      #pragma unroll
      for (int r = 0; r < 4; ++r) {
        int slot = mi * 4 + r;
        int row = row0 + wid * 32 + mi * 16 + q * 4 + r;
        out_idx[row] = i1f[slot];
        if (v2[slot] - v1[slot] < T_FLAG) {
          int p = atomicAdd(&flags[0], 1);
          if (p < NN) flags[1 + p] = row;
        }
      }
  }
}

// ---------- fixup: exactly-rounded f32 dot (via f64) + quantized formula ----------
__global__ __launch_bounds__(256)
void fixup_k(const float* __restrict__ z, const float* __restrict__ emb,
             const float* __restrict__ e2np, const float* __restrict__ z2np,
             const int* __restrict__ flags, float* __restrict__ out_idx) {
  __shared__ float zrow[C];
  __shared__ float bval[4];
  __shared__ int   bidx[4];
  int cnt = flags[0];
  if (cnt > NN) cnt = NN;
  for (int f = blockIdx.x; f < cnt; f += gridDim.x) {
    int n = flags[1 + f];
    int b = n >> 12, s = n & (SS - 1);
    int t = threadIdx.x;
    zrow[t] = z[((size_t)(b * C + t) << 12) + s];
    __syncthreads();
    float z2 = z2np[n];
    float best = 3.4e38f; int besti = 0x7fffffff;
    for (int kk = t; kk < K; kk += 256) {
      const float* er = emb + (size_t)kk * C;
      double acc = 0.0;
      #pragma unroll 4
      for (int c = 0; c < C; ++c)
        acc = fma((double)zrow[c], (double)er[c], acc);
      float g  = (float)acc;                          // RN f32 of exact dot
      float t1 = __fadd_rn(z2, e2np[kk]);
      float d  = __fsub_rn(t1, __fmul_rn(2.f, g));    // np's quantized score
      if (d < best) { best = d; besti = kk; }
    }
    #pragma unroll
    for (int off = 32; off; off >>= 1) {
      float ov = __shfl_down(best, off);
      int   oi = __shfl_down(besti, off);
      if (ov < best || (ov == best && oi < besti)) { best = ov; besti = oi; }
    }
    int lane = t & 63, w = t >> 6;
    if (lane == 0) { bval[w] = best; bidx[w] = besti; }
    __syncthreads();
    if (t == 0) {
      #pragma unroll
      for (int w2 = 1; w2 < 4; ++w2) {
        if (bval[w2] < best || (bval[w2] == best && bidx[w2] < besti)) {
          best = bval[w2]; besti = bidx[w2];
        }
      }
      out_idx[n] = (float)besti;
    }
    __syncthreads();
  }
}

// ---------- histogram from final idx ----------
__global__ void hist_k(const float* __restrict__ idxf, float* __restrict__ counts) {
  int n = blockIdx.x * 256 + threadIdx.x;
  atomicAdd(&counts[(int)idxf[n]], 1.0f);
}

// ---------- gather zq + loss accumulation ----------
__global__ __launch_bounds__(256)
void gather_loss_k(const float* __restrict__ z, const float* __restrict__ emb,
                   float* __restrict__ out, float* __restrict__ ws) {
  __shared__ float sc[4];
  int f = blockIdx.x * 256 + threadIdx.x;  // float4 id
  int i = f << 2;
  int b = i >> 20;
  int rem = i & ((1 << 20) - 1);
  int c = rem >> 12;
  int s = rem & (SS - 1);
  int n = (b << 12) | s;
  const float* idxf = out + OUT_IDX;
  float2 ia = *(const float2*)(idxf + n);
  float2 ib = *(const float2*)(idxf + n + 2);
  int i0 = (int)ia.x, i1 = (int)ia.y, i2 = (int)ib.x, i3 = (int)ib.y;
  float4 q;
  q.x = emb[(size_t)i0 * C + c];
  q.y = emb[(size_t)i1 * C + c];
  q.z = emb[(size_t)i2 * C + c];
  q.w = emb[(size_t)i3 * C + c];
  float4 zv = *(const float4*)(z + i);
  float dx = q.x - zv.x, dy = q.y - zv.y, dz = q.z - zv.z, dw = q.w - zv.w;
  float l = dx * dx + dy * dy + dz * dz + dw * dw;
  *(float4*)(out + i) = q;
  #pragma unroll
  for (int off = 32; off; off >>= 1) l += __shfl_down(l, off);
  int lane = threadIdx.x & 63, w = threadIdx.x >> 6;
  if (lane == 0) sc[w] = l;
  __syncthreads();
  if (threadIdx.x == 0)
    atomicAdd(&ws[WS_LOSS], sc[0] + sc[1] + sc[2] + sc[3]);
}

// ---------- finalize scalars ----------
__global__ void finalize_k(const float* __restrict__ ws, float* __restrict__ out) {
  __shared__ float sc[8];
  int t = threadIdx.x;
  float ent = 0.f;
  #pragma unroll
  for (int k = t; k < K; k += 256) {
    float em = ws[WS_CNT + k] * (1.0f / NN);
    ent += em * logf(em + 1e-10f);
  }
  float zd = ws[WS_ZSUM + t] * ws[WS_ESUM + t];
  #pragma unroll
  for (int off = 32; off; off >>= 1) {
    ent += __shfl_down(ent, off);
    zd  += __shfl_down(zd, off);
  }
  int lane = t & 63, w = t >> 6;
  if (lane == 0) { sc[w] = ent; sc[4 + w] = zd; }
  __syncthreads();
  if (t == 0) {
    ent = sc[0] + sc[1] + sc[2] + sc[3];
    zd  = sc[4] + sc[5] + sc[6] + sc[7];
    out[OUT_LOSS] = 1.25f * ws[WS_LOSS] * (1.0f / ZQ_ELEMS);  // (1+beta)*MSE
    out[OUT_PERP] = expf(-ent);
    out[OUT_MD]   = ws[WS_SZ2] * (1.0f / NN) + ws[WS_SE2] * (1.0f / K)
                  - 2.0f * zd * (1.0f / ((float)NN * (float)K));
  }
}

extern "C" void kernel_launch(void* const* d_in, const int* in_sizes, int n_in,
                              void* d_out, int out_size, void* d_ws, size_t ws_size,
                              hipStream_t stream) {
  const float* z   = (const float*)d_in[0];
  const float* emb = (const float*)d_in[1];
  float* out = (float*)d_out;
  float* ws  = (float*)d_ws;
  int* flags = (int*)(ws + WS_FLG);
  // zh/zl live in d_out's zq region; overwritten by gather_loss_k at the end.
  u16* zh_g = (u16*)d_out;
  u16* zl_g = zh_g + (size_t)ZQ_ELEMS;
  (void)in_sizes; (void)n_in; (void)out_size; (void)ws_size;

  hipMemsetAsync(d_ws, 0, (WS_FLG + 1) * sizeof(float), stream);
  e2_np_k<<<K / 256, 256, 0, stream>>>(emb, ws);
  emb_col_k<<<64, 256, 0, stream>>>(emb, ws);
  prep_z_k<<<NN / MROWS, 256, 0, stream>>>(z, ws, zh_g, zl_g);
  size_t lds = (size_t)(4 * BM * CH) * sizeof(u16) + BN * sizeof(float);
  vq_mfma_k<<<NN / BM, 256, lds, stream>>>(zh_g, zl_g, emb, ws + WS_E2R,
                                           out + OUT_IDX, flags);
  fixup_k<<<2048, 256, 0, stream>>>(z, emb, ws + WS_E2R, ws + WS_Z2N, flags, out + OUT_IDX);
  hist_k<<<NN / 256, 256, 0, stream>>>(out + OUT_IDX, ws + WS_CNT);
  gather_loss_k<<<ZQ_ELEMS / 1024, 256, 0, stream>>>(z, emb, out, ws);
  finalize_k<<<1, 256, 0, stream>>>(ws, out);
}